// Round 1
// baseline (210.691 us; speedup 1.0000x reference)
//
#include <hip/hip_runtime.h>

// Problem constants
#define NMOLS   256
#define NATOMS  32
#define TOTA    8192      // NMOLS*NATOMS
#define REPD    256
#define NPCAS   128
#define NSTACKS 32
#define NFEAT   4096
#define NELEM   4

// ws layout (bytes)
#define LIST_OFF 0          // int list[8192]
#define META_OFF 32768      // int meta[16]: counts[4], offsets[4], total
#define SUB_OFF  40960      // float sub[8192*128]

#define SCALE_C 0.029462782549439476f   // sqrt(128)/(3*128)  (coeff_norm * hnorm^2)
#define FEATN_C 0.022097086912079608f   // sqrt(2/4096)

__device__ __forceinline__ int elem_of(int z) {
  return (z == 1) ? 0 : (z == 6) ? 1 : (z == 7) ? 2 : (z == 8) ? 3 : -1;
}

// ---------------- K0: bucket atoms by element (deterministic), zero out ----------------
__global__ __launch_bounds__(256) void k0_bucket(const int* __restrict__ Z,
                                                 int* __restrict__ list,
                                                 int* __restrict__ meta,
                                                 float* __restrict__ out) {
  __shared__ int4 cntS[256];
  const int t = threadIdx.x;
  out[t] = 0.0f;                      // out_size == 256 == blockDim
  int c0 = 0, c1 = 0, c2 = 0, c3 = 0;
  #pragma unroll
  for (int k = 0; k < 32; ++k) {
    const int z = Z[k * 256 + t];     // coalesced
    c0 += (z == 1); c1 += (z == 6); c2 += (z == 7); c3 += (z == 8);
  }
  int4 v = make_int4(c0, c1, c2, c3);
  cntS[t] = v;
  __syncthreads();
  for (int step = 1; step < 256; step <<= 1) {   // Hillis-Steele inclusive scan
    int4 add = make_int4(0, 0, 0, 0);
    if (t >= step) add = cntS[t - step];
    __syncthreads();
    v.x += add.x; v.y += add.y; v.z += add.z; v.w += add.w;
    cntS[t] = v;
    __syncthreads();
  }
  const int4 tot = cntS[255];
  int o0 = v.x - c0;                                   // exclusive offsets for this thread
  int o1 = tot.x + v.y - c1;
  int o2 = tot.x + tot.y + v.z - c2;
  int o3 = tot.x + tot.y + tot.z + v.w - c3;
  #pragma unroll
  for (int k = 0; k < 32; ++k) {
    const int a = k * 256 + t;
    const int z = Z[a];
    if      (z == 1) list[o0++] = a;
    else if (z == 6) list[o1++] = a;
    else if (z == 7) list[o2++] = a;
    else if (z == 8) list[o3++] = a;
  }
  if (t == 0) {
    meta[0] = tot.x; meta[1] = tot.y; meta[2] = tot.z; meta[3] = tot.w;
    meta[4] = 0;
    meta[5] = tot.x;
    meta[6] = tot.x + tot.y;
    meta[7] = tot.x + tot.y + tot.z;
    meta[8] = tot.x + tot.y + tot.z + tot.w;
  }
}

// ---------------- K1: sub[pos][p] = rep[aid] . reductors[e][:,p] ----------------
// Block: one element e (blockIdx.y), 32 sorted atoms (blockIdx.x). 256 thr = (p 0..127) x (h 0..1).
__global__ __launch_bounds__(256) void k1_matvec(const float* __restrict__ rep,
                                                 const float* __restrict__ reductors,
                                                 const int* __restrict__ list,
                                                 const int* __restrict__ meta,
                                                 float* __restrict__ sub) {
  const int e = blockIdx.y;
  const int cnt = meta[e];
  const int off = meta[4 + e];
  const int start = blockIdx.x * 32;
  if (start >= cnt) return;
  const int n = min(32, cnt - start);
  const int t = threadIdx.x;
  const int p = t & 127, h = t >> 7;

  __shared__ int aidS[32];
  __shared__ float subS[32][128];
  if (t < 32) aidS[t] = (t < n) ? list[off + start + t] : 0;
  __syncthreads();

  int rbase[32];
  #pragma unroll
  for (int j = 0; j < 32; ++j)
    rbase[j] = __builtin_amdgcn_readfirstlane(aidS[j]) * 256;   // wave-uniform -> SGPR

  const float* red_e = reductors + e * (REPD * NPCAS);
  float part[32];
  #pragma unroll
  for (int j = 0; j < 32; ++j) part[j] = 0.0f;

  const int h128 = h * 128;
  for (int r4 = 0; r4 < 32; ++r4) {
    const int r0 = h128 + r4 * 4;
    const float rv0 = red_e[(r0 + 0) * 128 + p];
    const float rv1 = red_e[(r0 + 1) * 128 + p];
    const float rv2 = red_e[(r0 + 2) * 128 + p];
    const float rv3 = red_e[(r0 + 3) * 128 + p];
    #pragma unroll
    for (int j = 0; j < 32; ++j) {
      const float4 q = *(const float4*)(rep + rbase[j] + r0);   // uniform addr -> s_load
      part[j] = fmaf(q.w, rv3, fmaf(q.z, rv2, fmaf(q.y, rv1, fmaf(q.x, rv0, part[j]))));
    }
  }

  if (h == 0) {
    #pragma unroll
    for (int j = 0; j < 32; ++j) subS[j][p] = part[j];
  }
  __syncthreads();
  if (h == 1) {
    #pragma unroll
    for (int j = 0; j < 32; ++j)
      if (j < n) sub[(off + start + j) * 128 + p] = subS[j][p] + part[j];
  }
}

// ---------------- K2: SORF + cos + alpha-dot + atomic accumulate per mol ----------------
#define FSTAGE(x, m, sg) { float t_ = __shfl_xor((x), (m), 64); (x) = fmaf((x), (sg), t_); }
#define FW128(lo, hi) { \
  { float a_ = (lo) + (hi), b_ = (lo) - (hi); (lo) = a_; (hi) = b_; } \
  FSTAGE(lo, 1, sg1)  FSTAGE(hi, 1, sg1) \
  FSTAGE(lo, 2, sg2)  FSTAGE(hi, 2, sg2) \
  FSTAGE(lo, 4, sg4)  FSTAGE(hi, 4, sg4) \
  FSTAGE(lo, 8, sg8)  FSTAGE(hi, 8, sg8) \
  FSTAGE(lo, 16, sg16) FSTAGE(hi, 16, sg16) \
  FSTAGE(lo, 32, sg32) FSTAGE(hi, 32, sg32) }

__global__ __launch_bounds__(256) void k2_features(const float* __restrict__ sub,
                                                   const int* __restrict__ list,
                                                   const int* __restrict__ meta,
                                                   const int* __restrict__ Z,
                                                   const float* __restrict__ Dmat,
                                                   const float* __restrict__ bias,
                                                   const float* __restrict__ alpha,
                                                   float* __restrict__ out) {
  const int total = meta[8];
  const int w = threadIdx.x >> 6, lane = threadIdx.x & 63;
  const int pos0 = blockIdx.x * 8 + w * 2;
  if (pos0 >= total) return;
  const bool hasB = (pos0 + 1) < total;

  const float sg1  = (lane & 1)  ? -1.0f : 1.0f;
  const float sg2  = (lane & 2)  ? -1.0f : 1.0f;
  const float sg4  = (lane & 4)  ? -1.0f : 1.0f;
  const float sg8  = (lane & 8)  ? -1.0f : 1.0f;
  const float sg16 = (lane & 16) ? -1.0f : 1.0f;
  const float sg32 = (lane & 32) ? -1.0f : 1.0f;

  const int aidA = list[pos0];
  const int eA = elem_of(Z[aidA]);
  const float sAlo = sub[pos0 * 128 + lane];
  const float sAhi = sub[pos0 * 128 + 64 + lane];

  int aidB = aidA; int eB = 0; float sBlo = 0.0f, sBhi = 0.0f;
  if (hasB) {
    aidB = list[pos0 + 1];
    eB = elem_of(Z[aidB]);
    sBlo = sub[(pos0 + 1) * 128 + lane];
    sBhi = sub[(pos0 + 1) * 128 + 64 + lane];
  }

  const float* DeA = Dmat + eA * (2 * NSTACKS * NPCAS);
  const float* DeB = Dmat + eB * (2 * NSTACKS * NPCAS);
  const float* beA = bias + eA * NFEAT;
  const float* beB = bias + eB * NFEAT;

  float accA = 0.0f, accB = 0.0f;

  for (int s = 0; s < NSTACKS; ++s) {
    const float* dA0 = DeA + s * 128;
    const float* dA1 = DeA + (NSTACKS + s) * 128;
    const float* dB0 = DeB + s * 128;
    const float* dB1 = DeB + (NSTACKS + s) * 128;

    float Alo = sAlo * dA0[lane],      Ahi = sAhi * dA0[64 + lane];
    float Blo = sBlo * dB0[lane],      Bhi = sBhi * dB0[64 + lane];
    FW128(Alo, Ahi)
    FW128(Blo, Bhi)
    Alo *= dA1[lane];  Ahi *= dA1[64 + lane];
    Blo *= dB1[lane];  Bhi *= dB1[64 + lane];
    FW128(Alo, Ahi)
    FW128(Blo, Bhi)

    const int f0 = s * 128 + lane, f1 = f0 + 64;
    accA = fmaf(__cosf(fmaf(Alo, SCALE_C, beA[f0])), alpha[f0], accA);
    accA = fmaf(__cosf(fmaf(Ahi, SCALE_C, beA[f1])), alpha[f1], accA);
    accB = fmaf(__cosf(fmaf(Blo, SCALE_C, beB[f0])), alpha[f0], accB);
    accB = fmaf(__cosf(fmaf(Bhi, SCALE_C, beB[f1])), alpha[f1], accB);
  }

  #pragma unroll
  for (int o = 32; o > 0; o >>= 1) {
    accA += __shfl_xor(accA, o, 64);
    accB += __shfl_xor(accB, o, 64);
  }
  if (lane == 0) atomicAdd(out + (aidA >> 5), accA * FEATN_C);
  if (lane == 1 && hasB) atomicAdd(out + (aidB >> 5), accB * FEATN_C);
}

extern "C" void kernel_launch(void* const* d_in, const int* in_sizes, int n_in,
                              void* d_out, int out_size, void* d_ws, size_t ws_size,
                              hipStream_t stream) {
  const float* rep       = (const float*)d_in[0];
  const int*   Z         = (const int*)  d_in[1];
  const float* reductors = (const float*)d_in[2];
  const float* Dmat      = (const float*)d_in[3];
  const float* bias      = (const float*)d_in[4];
  const float* alpha     = (const float*)d_in[5];
  float* out = (float*)d_out;

  char* wsb = (char*)d_ws;
  int*   list = (int*)(wsb + LIST_OFF);
  int*   meta = (int*)(wsb + META_OFF);
  float* sub  = (float*)(wsb + SUB_OFF);

  k0_bucket<<<1, 256, 0, stream>>>(Z, list, meta, out);
  dim3 g1(256, 4);
  k1_matvec<<<g1, 256, 0, stream>>>(rep, reductors, list, meta, sub);
  k2_features<<<1024, 256, 0, stream>>>(sub, list, meta, Z, Dmat, bias, alpha, out);
}

// Round 2
// 93.803 us; speedup vs baseline: 2.2461x; 2.2461x over previous
//
#include <hip/hip_runtime.h>

// Problem constants
#define NMOLS   256
#define NATOMS  32
#define TOTA    8192      // NMOLS*NATOMS
#define REPD    256
#define NPCAS   128
#define NSTACKS 32
#define NFEAT   4096
#define NELEM   4

// ws layout (bytes)
#define LIST_OFF 0          // int list[8192]
#define META_OFF 32768      // int meta[16]: counts[4], offsets[4], total
#define SUB_OFF  40960      // float sub[8192*128]

#define SCALE_C 0.029462782549439476f   // sqrt(128)/(3*128)  (coeff_norm * hnorm^2)
#define FEATN_C 0.022097086912079608f   // sqrt(2/4096)

__device__ __forceinline__ int elem_of(int z) {
  return (z == 1) ? 0 : (z == 6) ? 1 : (z == 7) ? 2 : (z == 8) ? 3 : -1;
}

// ---------------- K0: bucket atoms by element (deterministic), zero out ----------------
__global__ __launch_bounds__(256) void k0_bucket(const int* __restrict__ Z,
                                                 int* __restrict__ list,
                                                 int* __restrict__ meta,
                                                 float* __restrict__ out) {
  __shared__ int4 cntS[256];
  const int t = threadIdx.x;
  out[t] = 0.0f;                      // out_size == 256 == blockDim
  int c0 = 0, c1 = 0, c2 = 0, c3 = 0;
  #pragma unroll
  for (int k = 0; k < 32; ++k) {
    const int z = Z[k * 256 + t];     // coalesced
    c0 += (z == 1); c1 += (z == 6); c2 += (z == 7); c3 += (z == 8);
  }
  int4 v = make_int4(c0, c1, c2, c3);
  cntS[t] = v;
  __syncthreads();
  for (int step = 1; step < 256; step <<= 1) {   // Hillis-Steele inclusive scan
    int4 add = make_int4(0, 0, 0, 0);
    if (t >= step) add = cntS[t - step];
    __syncthreads();
    v.x += add.x; v.y += add.y; v.z += add.z; v.w += add.w;
    cntS[t] = v;
    __syncthreads();
  }
  const int4 tot = cntS[255];
  int o0 = v.x - c0;                                   // exclusive offsets for this thread
  int o1 = tot.x + v.y - c1;
  int o2 = tot.x + tot.y + v.z - c2;
  int o3 = tot.x + tot.y + tot.z + v.w - c3;
  #pragma unroll
  for (int k = 0; k < 32; ++k) {
    const int a = k * 256 + t;
    const int z = Z[a];
    if      (z == 1) list[o0++] = a;
    else if (z == 6) list[o1++] = a;
    else if (z == 7) list[o2++] = a;
    else if (z == 8) list[o3++] = a;
  }
  if (t == 0) {
    meta[0] = tot.x; meta[1] = tot.y; meta[2] = tot.z; meta[3] = tot.w;
    meta[4] = 0;
    meta[5] = tot.x;
    meta[6] = tot.x + tot.y;
    meta[7] = tot.x + tot.y + tot.z;
    meta[8] = tot.x + tot.y + tot.z + tot.w;
  }
}

// ---------------- K1: sub[pos][p] = rep[aid] . reductors[e][:,p] ----------------
// Block: element e = blockIdx.y, 32 sorted atoms. Stage rep rows in LDS (coalesced),
// then 256 thr = (p 0..127) x (jh 0..1): each thread accumulates 16 atoms over full K=256,
// reading rep via wave-uniform ds_read_b128 broadcasts in chunks of 8 (pipelines, ~64 VGPR).
__global__ __launch_bounds__(256) void k1_matvec(const float* __restrict__ rep,
                                                 const float* __restrict__ reductors,
                                                 const int* __restrict__ list,
                                                 const int* __restrict__ meta,
                                                 float* __restrict__ sub) {
  const int e = blockIdx.y;
  const int cnt = meta[e];
  const int off = meta[4 + e];
  const int start = blockIdx.x * 32;
  if (start >= cnt) return;
  const int n = min(32, cnt - start);
  const int t = threadIdx.x;

  __shared__ int aidS[32];
  __shared__ float repS[32][256];
  if (t < 32) aidS[t] = list[off + start + (t < n ? t : 0)];
  __syncthreads();

  // stage rep rows: 8 passes x 4 rows; each wave loads one contiguous 1KB row segment
  #pragma unroll
  for (int pass = 0; pass < 8; ++pass) {
    const int j = pass * 4 + (t >> 6);          // wave-uniform row
    const int c = (t & 63) * 4;
    *(float4*)&repS[j][c] = *(const float4*)(rep + aidS[j] * 256 + c);
  }
  __syncthreads();

  const int p = t & 127;
  const int jh = (t >> 7) * 16;                 // atoms jh..jh+15
  const float* red_e = reductors + e * (REPD * NPCAS);

  float part[16];
  #pragma unroll
  for (int j = 0; j < 16; ++j) part[j] = 0.0f;

  for (int r4 = 0; r4 < 64; ++r4) {
    const int r0 = r4 * 4;
    const float rv0 = red_e[(r0 + 0) * 128 + p];
    const float rv1 = red_e[(r0 + 1) * 128 + p];
    const float rv2 = red_e[(r0 + 2) * 128 + p];
    const float rv3 = red_e[(r0 + 3) * 128 + p];
    #pragma unroll
    for (int jc = 0; jc < 2; ++jc) {
      float4 q[8];
      #pragma unroll
      for (int u = 0; u < 8; ++u)
        q[u] = *(const float4*)&repS[jh + jc * 8 + u][r0];   // uniform addr -> broadcast
      #pragma unroll
      for (int u = 0; u < 8; ++u) {
        const int j = jc * 8 + u;
        part[j] = fmaf(q[u].w, rv3, fmaf(q[u].z, rv2, fmaf(q[u].y, rv1, fmaf(q[u].x, rv0, part[j]))));
      }
    }
  }

  #pragma unroll
  for (int j = 0; j < 16; ++j) {
    const int a = jh + j;
    if (a < n) sub[(off + start + a) * 128 + p] = part[j];
  }
}

// ---------------- K2: SORF + cos + alpha-dot + atomic accumulate per mol ----------------
template <int CTRL>
__device__ __forceinline__ float dppx(float x) {
  return __int_as_float(__builtin_amdgcn_update_dpp(0, __float_as_int(x), CTRL, 0xF, 0xF, true));
}
template <int OFF>
__device__ __forceinline__ float swzx(float x) {
  return __int_as_float(__builtin_amdgcn_ds_swizzle(__float_as_int(x), OFF));
}

// butterflies: x' = x*sg + partner
#define BFLY_DPP(x, CTRL, sg) { float t_ = dppx<CTRL>(x); (x) = fmaf((x), (sg), t_); }
#define BFLY_SWZ(x, OFF, sg)  { float t_ = swzx<OFF>(x);  (x) = fmaf((x), (sg), t_); }
#define BFLY_SHF(x, m, sg)    { float t_ = __shfl_xor((x), (m), 64); (x) = fmaf((x), (sg), t_); }

// xor1: quad_perm[1,0,3,2]=0xB1; xor2: quad_perm[2,3,0,1]=0x4E; xor8: row_ror:8=0x128
// xor4: ds_swizzle (4<<10)|0x1F; xor16: ds_swizzle (16<<10)|0x1F; xor32: shfl (bpermute)
#define FW128(lo, hi) { \
  { float a_ = (lo) + (hi), b_ = (lo) - (hi); (lo) = a_; (hi) = b_; } \
  BFLY_DPP(lo, 0xB1, sg1)    BFLY_DPP(hi, 0xB1, sg1) \
  BFLY_DPP(lo, 0x4E, sg2)    BFLY_DPP(hi, 0x4E, sg2) \
  BFLY_SWZ(lo, 0x101F, sg4)  BFLY_SWZ(hi, 0x101F, sg4) \
  BFLY_DPP(lo, 0x128, sg8)   BFLY_DPP(hi, 0x128, sg8) \
  BFLY_SWZ(lo, 0x401F, sg16) BFLY_SWZ(hi, 0x401F, sg16) \
  BFLY_SHF(lo, 32, sg32)     BFLY_SHF(hi, 32, sg32) }

__global__ __launch_bounds__(256) void k2_features(const float* __restrict__ sub,
                                                   const int* __restrict__ list,
                                                   const int* __restrict__ meta,
                                                   const int* __restrict__ Z,
                                                   const float* __restrict__ Dmat,
                                                   const float* __restrict__ bias,
                                                   const float* __restrict__ alpha,
                                                   float* __restrict__ out) {
  const int total = meta[8];
  const int w = threadIdx.x >> 6, lane = threadIdx.x & 63;
  const int pos0 = blockIdx.x * 8 + w * 2;
  if (pos0 >= total) return;
  const bool hasB = (pos0 + 1) < total;

  const float sg1  = (lane & 1)  ? -1.0f : 1.0f;
  const float sg2  = (lane & 2)  ? -1.0f : 1.0f;
  const float sg4  = (lane & 4)  ? -1.0f : 1.0f;
  const float sg8  = (lane & 8)  ? -1.0f : 1.0f;
  const float sg16 = (lane & 16) ? -1.0f : 1.0f;
  const float sg32 = (lane & 32) ? -1.0f : 1.0f;

  const int aidA = list[pos0];
  const int eA = elem_of(Z[aidA]);
  const float sAlo = sub[pos0 * 128 + lane];
  const float sAhi = sub[pos0 * 128 + 64 + lane];

  int aidB = aidA; int eB = 0; float sBlo = 0.0f, sBhi = 0.0f;
  if (hasB) {
    aidB = list[pos0 + 1];
    eB = elem_of(Z[aidB]);
    sBlo = sub[(pos0 + 1) * 128 + lane];
    sBhi = sub[(pos0 + 1) * 128 + 64 + lane];
  }

  const float* DeA = Dmat + eA * (2 * NSTACKS * NPCAS);
  const float* DeB = Dmat + eB * (2 * NSTACKS * NPCAS);
  const float* beA = bias + eA * NFEAT;
  const float* beB = bias + eB * NFEAT;

  float accA = 0.0f, accB = 0.0f;

  for (int s = 0; s < NSTACKS; ++s) {
    const float* dA0 = DeA + s * 128;
    const float* dA1 = DeA + (NSTACKS + s) * 128;
    const float* dB0 = DeB + s * 128;
    const float* dB1 = DeB + (NSTACKS + s) * 128;

    float Alo = sAlo * dA0[lane],      Ahi = sAhi * dA0[64 + lane];
    float Blo = sBlo * dB0[lane],      Bhi = sBhi * dB0[64 + lane];
    FW128(Alo, Ahi)
    FW128(Blo, Bhi)
    Alo *= dA1[lane];  Ahi *= dA1[64 + lane];
    Blo *= dB1[lane];  Bhi *= dB1[64 + lane];
    FW128(Alo, Ahi)
    FW128(Blo, Bhi)

    const int f0 = s * 128 + lane, f1 = f0 + 64;
    accA = fmaf(__cosf(fmaf(Alo, SCALE_C, beA[f0])), alpha[f0], accA);
    accA = fmaf(__cosf(fmaf(Ahi, SCALE_C, beA[f1])), alpha[f1], accA);
    accB = fmaf(__cosf(fmaf(Blo, SCALE_C, beB[f0])), alpha[f0], accB);
    accB = fmaf(__cosf(fmaf(Bhi, SCALE_C, beB[f1])), alpha[f1], accB);
  }

  #pragma unroll
  for (int o = 32; o > 0; o >>= 1) {
    accA += __shfl_xor(accA, o, 64);
    accB += __shfl_xor(accB, o, 64);
  }
  if (lane == 0) atomicAdd(out + (aidA >> 5), accA * FEATN_C);
  if (lane == 1 && hasB) atomicAdd(out + (aidB >> 5), accB * FEATN_C);
}

extern "C" void kernel_launch(void* const* d_in, const int* in_sizes, int n_in,
                              void* d_out, int out_size, void* d_ws, size_t ws_size,
                              hipStream_t stream) {
  const float* rep       = (const float*)d_in[0];
  const int*   Z         = (const int*)  d_in[1];
  const float* reductors = (const float*)d_in[2];
  const float* Dmat      = (const float*)d_in[3];
  const float* bias      = (const float*)d_in[4];
  const float* alpha     = (const float*)d_in[5];
  float* out = (float*)d_out;

  char* wsb = (char*)d_ws;
  int*   list = (int*)(wsb + LIST_OFF);
  int*   meta = (int*)(wsb + META_OFF);
  float* sub  = (float*)(wsb + SUB_OFF);

  k0_bucket<<<1, 256, 0, stream>>>(Z, list, meta, out);
  dim3 g1(256, 4);
  k1_matvec<<<g1, 256, 0, stream>>>(rep, reductors, list, meta, sub);
  k2_features<<<1024, 256, 0, stream>>>(sub, list, meta, Z, Dmat, bias, alpha, out);
}

// Round 3
// 76.414 us; speedup vs baseline: 2.7572x; 1.2276x over previous
//
#include <hip/hip_runtime.h>

// Problem constants
#define NMOLS   256
#define NATOMS  32
#define REPD    256
#define NPCAS   128
#define NSTACKS 32
#define NFEAT   4096
#define NELEM   4

// ws layout (bytes)
#define LIST_OFF 0          // int list[8192]
#define META_OFF 32768      // int meta[16]
#define SUB_OFF  40960      // float sub[8192*128]

#define SCALE_C 0.029462782549439476f   // sqrt(128)/(3*128)
#define FEATN_C 0.022097086912079608f   // sqrt(2/4096)

__device__ __forceinline__ int elem_of(int z) {
  return (z == 1) ? 0 : (z == 6) ? 1 : (z == 7) ? 2 : (z == 8) ? 3 : -1;
}

// ---------------- K0: bucket atoms by element (deterministic), zero out ----------------
__global__ __launch_bounds__(256) void k0_bucket(const int* __restrict__ Z,
                                                 int* __restrict__ list,
                                                 int* __restrict__ meta,
                                                 float* __restrict__ out) {
  __shared__ int4 cntS[256];
  const int t = threadIdx.x;
  out[t] = 0.0f;
  int c0 = 0, c1 = 0, c2 = 0, c3 = 0;
  #pragma unroll
  for (int k = 0; k < 32; ++k) {
    const int z = Z[k * 256 + t];
    c0 += (z == 1); c1 += (z == 6); c2 += (z == 7); c3 += (z == 8);
  }
  int4 v = make_int4(c0, c1, c2, c3);
  cntS[t] = v;
  __syncthreads();
  for (int step = 1; step < 256; step <<= 1) {
    int4 add = make_int4(0, 0, 0, 0);
    if (t >= step) add = cntS[t - step];
    __syncthreads();
    v.x += add.x; v.y += add.y; v.z += add.z; v.w += add.w;
    cntS[t] = v;
    __syncthreads();
  }
  const int4 tot = cntS[255];
  int o0 = v.x - c0;
  int o1 = tot.x + v.y - c1;
  int o2 = tot.x + tot.y + v.z - c2;
  int o3 = tot.x + tot.y + tot.z + v.w - c3;
  #pragma unroll
  for (int k = 0; k < 32; ++k) {
    const int a = k * 256 + t;
    const int z = Z[a];
    if      (z == 1) list[o0++] = a;
    else if (z == 6) list[o1++] = a;
    else if (z == 7) list[o2++] = a;
    else if (z == 8) list[o3++] = a;
  }
  if (t == 0) {
    meta[0] = tot.x; meta[1] = tot.y; meta[2] = tot.z; meta[3] = tot.w;
    meta[4] = 0;
    meta[5] = tot.x;
    meta[6] = tot.x + tot.y;
    meta[7] = tot.x + tot.y + tot.z;
    meta[8] = tot.x + tot.y + tot.z + tot.w;
  }
}

// ---------------- K1: register-tiled matvec ----------------
// Block: 64 atoms x 128 p. 256 thr = 8 jq (8 atoms) x 32 pq (4 p). 32 acc/thread.
// rep staged in LDS per K-half (32KB); red read from global (L2-resident, coalesced b128).
__global__ __launch_bounds__(256) void k1_matvec(const float* __restrict__ rep,
                                                 const float* __restrict__ reductors,
                                                 const int* __restrict__ list,
                                                 const int* __restrict__ meta,
                                                 float* __restrict__ sub) {
  const int e = blockIdx.y;
  const int cnt = meta[e];
  const int off = meta[4 + e];
  const int start = blockIdx.x * 64;
  if (start >= cnt) return;
  const int n = min(64, cnt - start);
  const int t = threadIdx.x;

  __shared__ int aidS[64];
  __shared__ float repS[64][128];     // 32 KB, one K-half at a time

  if (t < 64) aidS[t] = list[off + start + (t < n ? t : 0)];

  const int pq = t & 31, jq = t >> 5;
  const int p0 = pq * 4, j0 = jq * 8;
  const float* red_e = reductors + e * (REPD * NPCAS);

  float acc[8][4];
  #pragma unroll
  for (int j = 0; j < 8; ++j)
    #pragma unroll
    for (int q = 0; q < 4; ++q) acc[j][q] = 0.0f;

  for (int kh = 0; kh < 2; ++kh) {
    __syncthreads();
    // stage 64 rows x 128 floats = 2048 quads; 8 iters x 256 thr, coalesced per wave
    #pragma unroll
    for (int it = 0; it < 8; ++it) {
      const int idx = it * 256 + t;
      const int row = idx >> 5;          // 32 quads per row
      const int q   = idx & 31;
      *(float4*)&repS[row][q * 4] =
          *(const float4*)(rep + aidS[row] * 256 + kh * 128 + q * 4);
    }
    __syncthreads();

    const float* redk = red_e + (kh * 128) * 128 + p0;
    for (int r0 = 0; r0 < 128; r0 += 4) {
      const float4 rv0 = *(const float4*)(redk + (r0 + 0) * 128);
      const float4 rv1 = *(const float4*)(redk + (r0 + 1) * 128);
      const float4 rv2 = *(const float4*)(redk + (r0 + 2) * 128);
      const float4 rv3 = *(const float4*)(redk + (r0 + 3) * 128);
      float4 rp[8];
      #pragma unroll
      for (int j = 0; j < 8; ++j)
        rp[j] = *(const float4*)&repS[j0 + j][r0];   // 2 distinct rows/wave: free 2-way
      #pragma unroll
      for (int j = 0; j < 8; ++j) {
        acc[j][0] = fmaf(rp[j].w, rv3.x, fmaf(rp[j].z, rv2.x, fmaf(rp[j].y, rv1.x, fmaf(rp[j].x, rv0.x, acc[j][0]))));
        acc[j][1] = fmaf(rp[j].w, rv3.y, fmaf(rp[j].z, rv2.y, fmaf(rp[j].y, rv1.y, fmaf(rp[j].x, rv0.y, acc[j][1]))));
        acc[j][2] = fmaf(rp[j].w, rv3.z, fmaf(rp[j].z, rv2.z, fmaf(rp[j].y, rv1.z, fmaf(rp[j].x, rv0.z, acc[j][2]))));
        acc[j][3] = fmaf(rp[j].w, rv3.w, fmaf(rp[j].z, rv2.w, fmaf(rp[j].y, rv1.w, fmaf(rp[j].x, rv0.w, acc[j][3]))));
      }
    }
  }

  #pragma unroll
  for (int j = 0; j < 8; ++j) {
    const int a = j0 + j;
    if (a < n) {
      float4 v = make_float4(acc[j][0], acc[j][1], acc[j][2], acc[j][3]);
      *(float4*)(sub + (size_t)(off + start + a) * 128 + p0) = v;
    }
  }
}

// ---------------- K2: SORF + cos + alpha-dot + atomic accumulate per mol ----------------
template <int CTRL>
__device__ __forceinline__ float dppx(float x) {
  return __int_as_float(__builtin_amdgcn_update_dpp(0, __float_as_int(x), CTRL, 0xF, 0xF, true));
}
template <int OFF>
__device__ __forceinline__ float swzx(float x) {
  return __int_as_float(__builtin_amdgcn_ds_swizzle(__float_as_int(x), OFF));
}

#define BFLY_DPP(x, CTRL, sg) { float t_ = dppx<CTRL>(x); (x) = fmaf((x), (sg), t_); }
#define BFLY_SWZ(x, OFF, sg)  { float t_ = swzx<OFF>(x);  (x) = fmaf((x), (sg), t_); }

// gfx950 VALU half-swaps: A'[odd16] <-> B[even16] (and 32-lane variant).
#define SWAP16(a, b) asm("v_permlane16_swap_b32 %0, %1" : "+v"(a), "+v"(b));
#define SWAP32(a, b) asm("v_permlane32_swap_b32 %0, %1" : "+v"(a), "+v"(b));
// xor16/xor32 butterfly on BOTH regs via swap trick: 4 VALU, 0 LDS, no sign masks.
#define XST16(lo, hi) { SWAP16(lo, hi) float s_ = (lo) + (hi), d_ = (lo) - (hi); SWAP16(s_, d_) (lo) = s_; (hi) = d_; }
#define XST32(lo, hi) { SWAP32(lo, hi) float s_ = (lo) + (hi), d_ = (lo) - (hi); SWAP32(s_, d_) (lo) = s_; (hi) = d_; }

// xor1: quad_perm 0xB1 (DPP); xor2: 0x4E (DPP); xor4: ds_swizzle; xor8: row_ror:8 (DPP);
// xor16/xor32: permlane swap trick (VALU); bit6: register add/sub.
#define FW128(lo, hi) { \
  { float a_ = (lo) + (hi), b_ = (lo) - (hi); (lo) = a_; (hi) = b_; } \
  BFLY_DPP(lo, 0xB1, sg1)    BFLY_DPP(hi, 0xB1, sg1) \
  BFLY_DPP(lo, 0x4E, sg2)    BFLY_DPP(hi, 0x4E, sg2) \
  BFLY_SWZ(lo, 0x101F, sg4)  BFLY_SWZ(hi, 0x101F, sg4) \
  BFLY_DPP(lo, 0x128, sg8)   BFLY_DPP(hi, 0x128, sg8) \
  XST16(lo, hi) \
  XST32(lo, hi) }

__global__ __launch_bounds__(256) void k2_features(const float* __restrict__ sub,
                                                   const int* __restrict__ list,
                                                   const int* __restrict__ meta,
                                                   const int* __restrict__ Z,
                                                   const float* __restrict__ Dmat,
                                                   const float* __restrict__ bias,
                                                   const float* __restrict__ alpha,
                                                   float* __restrict__ out) {
  const int total = meta[8];
  const int w = threadIdx.x >> 6, lane = threadIdx.x & 63;
  const int pos0 = blockIdx.x * 8 + w * 2;
  if (pos0 >= total) return;
  const bool hasB = (pos0 + 1) < total;

  const float sg1 = (lane & 1) ? -1.0f : 1.0f;
  const float sg2 = (lane & 2) ? -1.0f : 1.0f;
  const float sg4 = (lane & 4) ? -1.0f : 1.0f;
  const float sg8 = (lane & 8) ? -1.0f : 1.0f;

  const int aidA = list[pos0];
  const int eA = elem_of(Z[aidA]);
  const float sAlo = sub[(size_t)pos0 * 128 + lane];
  const float sAhi = sub[(size_t)pos0 * 128 + 64 + lane];

  int aidB = aidA; int eB = 0; float sBlo = 0.0f, sBhi = 0.0f;
  if (hasB) {
    aidB = list[pos0 + 1];
    eB = elem_of(Z[aidB]);
    sBlo = sub[(size_t)(pos0 + 1) * 128 + lane];
    sBhi = sub[(size_t)(pos0 + 1) * 128 + 64 + lane];
  }

  const float* DeA = Dmat + eA * (2 * NSTACKS * NPCAS);
  const float* DeB = Dmat + eB * (2 * NSTACKS * NPCAS);
  const float* beA = bias + eA * NFEAT;
  const float* beB = bias + eB * NFEAT;

  float accA = 0.0f, accB = 0.0f;

  for (int s = 0; s < NSTACKS; ++s) {
    const float* dA0 = DeA + s * 128;
    const float* dA1 = DeA + (NSTACKS + s) * 128;
    const float* dB0 = DeB + s * 128;
    const float* dB1 = DeB + (NSTACKS + s) * 128;

    float Alo = sAlo * dA0[lane],      Ahi = sAhi * dA0[64 + lane];
    float Blo = sBlo * dB0[lane],      Bhi = sBhi * dB0[64 + lane];
    FW128(Alo, Ahi)
    FW128(Blo, Bhi)
    Alo *= dA1[lane];  Ahi *= dA1[64 + lane];
    Blo *= dB1[lane];  Bhi *= dB1[64 + lane];
    FW128(Alo, Ahi)
    FW128(Blo, Bhi)

    const int f0 = s * 128 + lane, f1 = f0 + 64;
    accA = fmaf(__cosf(fmaf(Alo, SCALE_C, beA[f0])), alpha[f0], accA);
    accA = fmaf(__cosf(fmaf(Ahi, SCALE_C, beA[f1])), alpha[f1], accA);
    accB = fmaf(__cosf(fmaf(Blo, SCALE_C, beB[f0])), alpha[f0], accB);
    accB = fmaf(__cosf(fmaf(Bhi, SCALE_C, beB[f1])), alpha[f1], accB);
  }

  #pragma unroll
  for (int o = 32; o > 0; o >>= 1) {
    accA += __shfl_xor(accA, o, 64);
    accB += __shfl_xor(accB, o, 64);
  }
  if (lane == 0) atomicAdd(out + (aidA >> 5), accA * FEATN_C);
  if (lane == 1 && hasB) atomicAdd(out + (aidB >> 5), accB * FEATN_C);
}

extern "C" void kernel_launch(void* const* d_in, const int* in_sizes, int n_in,
                              void* d_out, int out_size, void* d_ws, size_t ws_size,
                              hipStream_t stream) {
  const float* rep       = (const float*)d_in[0];
  const int*   Z         = (const int*)  d_in[1];
  const float* reductors = (const float*)d_in[2];
  const float* Dmat      = (const float*)d_in[3];
  const float* bias      = (const float*)d_in[4];
  const float* alpha     = (const float*)d_in[5];
  float* out = (float*)d_out;

  char* wsb = (char*)d_ws;
  int*   list = (int*)(wsb + LIST_OFF);
  int*   meta = (int*)(wsb + META_OFF);
  float* sub  = (float*)(wsb + SUB_OFF);

  k0_bucket<<<1, 256, 0, stream>>>(Z, list, meta, out);
  dim3 g1(32, 4);                       // 64-atom tiles; cnt/elem ~1638 << 2048
  k1_matvec<<<g1, 256, 0, stream>>>(rep, reductors, list, meta, sub);
  k2_features<<<1024, 256, 0, stream>>>(sub, list, meta, Z, Dmat, bias, alpha, out);
}